// Round 12
// baseline (567.989 us; speedup 1.0000x reference)
//
#include <hip/hip_runtime.h>
#include <cstdint>
#include <cmath>

#define HID 32
#define GATES 96  // 3*HID
#define F 128
#define CHUNK 256
#define NCOPY 8   // XCD-privatized histogram copies

typedef float nfloat2 __attribute__((ext_vector_type(2)));

__device__ inline unsigned f2b(float x) {   // f32 -> bf16 (RNE)
    unsigned u = __float_as_uint(x);
    return (u + 0x7FFFu + ((u >> 16) & 1u)) >> 16;
}

// ws layout (float units): xwh[N*48] | sorted[E*2] | dinv[N] | cnt[N] | off[N] | csum[nchunk] | cnt8[8N] | pb[8N]
// rank[E] (u32) OVERLAYS xwh (dead before k_gemm writes xwh).

// privatized histogram: block b updates copy b&7 -> counters stay XCD-local
__global__ __launch_bounds__(256) void k_hist(const int* __restrict__ ei_dst,
                                              unsigned* __restrict__ cnt8,
                                              unsigned* __restrict__ rank, int N, int E) {
    int e = blockIdx.x * 256 + threadIdx.x;
    if (e >= E) return;
    int copy = blockIdx.x & (NCOPY - 1);
    rank[e] = atomicAdd(&cnt8[(size_t)copy * N + ei_dst[e]], 1u);
}

// cnt[i] = sum over copies; csum[chunk] = chunk total
__global__ __launch_bounds__(256) void k_chunksum(const unsigned* __restrict__ cnt8,
                                                  unsigned* __restrict__ cnt,
                                                  unsigned* __restrict__ csum, int N) {
    __shared__ unsigned s[256];
    int i = blockIdx.x * 256 + threadIdx.x;
    unsigned v = 0;
    if (i < N) {
        #pragma unroll
        for (int c = 0; c < NCOPY; ++c) v += cnt8[(size_t)c * N + i];
        cnt[i] = v;
    }
    s[threadIdx.x] = v;
    __syncthreads();
    for (int off = 128; off > 0; off >>= 1) {
        if (threadIdx.x < off) s[threadIdx.x] += s[threadIdx.x + off];
        __syncthreads();
    }
    if (threadIdx.x == 0) csum[blockIdx.x] = s[0];
}

__global__ __launch_bounds__(1024) void k_scanchunks(unsigned* __restrict__ csum, int nc) {
    __shared__ unsigned s[1024];
    int t = threadIdx.x;
    unsigned v = (t < nc) ? csum[t] : 0u;
    s[t] = v;
    __syncthreads();
    for (int o = 1; o < 1024; o <<= 1) {
        unsigned x = s[t];
        if (t >= o) x += s[t - o];
        __syncthreads();
        s[t] = x;
        __syncthreads();
    }
    if (t < nc) csum[t] = s[t] - v;   // exclusive
}

// off[i] = global exclusive scan; pb[c][i] = off[i] + prefix of copies
__global__ __launch_bounds__(256) void k_scanapply(const unsigned* __restrict__ cnt,
                                                   const unsigned* __restrict__ cnt8,
                                                   const unsigned* __restrict__ csum,
                                                   unsigned* __restrict__ off,
                                                   unsigned* __restrict__ pb, int N) {
    __shared__ unsigned s[2][256];
    int t = threadIdx.x, i = blockIdx.x * 256 + t;
    unsigned v = (i < N) ? cnt[i] : 0u;
    int cur = 0;
    s[0][t] = v;
    __syncthreads();
    for (int o = 1; o < 256; o <<= 1) {
        unsigned x = s[cur][t];
        if (t >= o) x += s[cur][t - o];
        s[cur ^ 1][t] = x;
        cur ^= 1;
        __syncthreads();
    }
    unsigned excl = s[cur][t] - v + csum[blockIdx.x];
    if (i < N) {
        off[i] = excl;
        unsigned run = excl;
        #pragma unroll
        for (int c = 0; c < NCOPY; ++c) {
            pb[(size_t)c * N + i] = run;
            run += cnt8[(size_t)c * N + i];
        }
    }
}

// atomic-free permute: slot = pb[copy][d] + rank[e]
__global__ __launch_bounds__(256) void k_permute(const int* __restrict__ ei,
        const float* __restrict__ w, const unsigned* __restrict__ pb,
        const unsigned* __restrict__ rank, float2* __restrict__ sorted, int N, int E) {
    int e = blockIdx.x * 256 + threadIdx.x;
    if (e >= E) return;
    int copy = blockIdx.x & (NCOPY - 1);
    int s = ei[e];
    int d = ei[(size_t)E + e];
    unsigned p = pb[(size_t)copy * N + d] + rank[e];
    sorted[p] = make_float2(__int_as_float(s), w[e]);
}

// dinv[n] = rsqrt(1 + sum w over CSR segment)
__global__ __launch_bounds__(256) void k_degsum(const unsigned* __restrict__ off,
        const unsigned* __restrict__ cnt, const float2* __restrict__ sorted,
        float* __restrict__ dinv, int N) {
    int l = threadIdx.x & 31;
    int n = blockIdx.x * 8 + (threadIdx.x >> 5);
    if (n >= N) return;
    unsigned base = off[n], len = cnt[n];
    float s = 0.0f;
    for (unsigned i = l; i < len; i += 32) s += sorted[base + i].y;
    #pragma unroll
    for (int o = 16; o >= 1; o >>= 1) s += __shfl_xor(s, o, 32);
    if (l == 0) dinv[n] = rsqrtf(1.0f + s);
}

// xwh[n][c] (bf16) = x[n][:] @ [Wz|Wr|Wh][:, c]
#define GR 16
__global__ __launch_bounds__(256) void k_gemm(const float* __restrict__ x,
        const float* __restrict__ Wz, const float* __restrict__ Wr, const float* __restrict__ Wh,
        unsigned* __restrict__ xwh, int N) {
    __shared__ float Wl[F * GATES];
    __shared__ float xs[GR][F + 1];
    int tid = threadIdx.x;
    for (int i = tid; i < F * GATES; i += 256) {
        int k = i / GATES, c = i % GATES;
        float v;
        if (c < 32)      v = Wz[k * 32 + c];
        else if (c < 64) v = Wr[k * 32 + (c - 32)];
        else             v = Wh[k * 32 + (c - 64)];
        Wl[i] = v;
    }
    int r_local = tid / 16;
    int cb = tid % 16;
    int ntiles = (N + GR - 1) / GR;
    for (int t = blockIdx.x; t < ntiles; t += gridDim.x) {
        int row0 = t * GR;
        __syncthreads();
        for (int i = tid; i < GR * F; i += 256) {
            int r = i / F, k = i % F;
            int g = row0 + r;
            xs[r][k] = (g < N) ? x[(size_t)g * F + k] : 0.0f;
        }
        __syncthreads();
        int grow = row0 + r_local;
        if (grow < N) {
            float acc[6] = {0, 0, 0, 0, 0, 0};
            for (int k = 0; k < F; ++k) {
                float xv = xs[r_local][k];
                const float* wr = &Wl[k * GATES + cb * 6];
                #pragma unroll
                for (int j = 0; j < 6; ++j) acc[j] += xv * wr[j];
            }
            unsigned* o = xwh + (size_t)grow * 48 + cb * 3;
            o[0] = f2b(acc[0]) | (f2b(acc[1]) << 16);
            o[1] = f2b(acc[2]) | (f2b(acc[3]) << 16);
            o[2] = f2b(acc[4]) | (f2b(acc[5]) << 16);
        }
    }
}

// one 32-lane group per dst node, two 16-lane halves. 2-deep software pipeline:
// issue BLK(b+8)'s four dwordx3 gathers BEFORE consuming BLK(b) -> ~8 loads in flight.
__global__ __launch_bounds__(256, 6) void k_fused(
        const unsigned* __restrict__ off, const unsigned* __restrict__ cnt,
        const float2* __restrict__ sorted,
        const unsigned* __restrict__ xwh, const float* __restrict__ dinv, const float* __restrict__ Hin,
        const float* __restrict__ bz, const float* __restrict__ br, const float* __restrict__ bh,
        const float* __restrict__ Lzw, const float* __restrict__ Lzb,
        const float* __restrict__ Lrw, const float* __restrict__ Lrb,
        const float* __restrict__ Lhw, const float* __restrict__ Lhb,
        const float* __restrict__ linw, const float* __restrict__ linb,
        float* __restrict__ out_probs, float* __restrict__ out_H, int N) {
    int tid = threadIdx.x;
    int l = tid & 31;
    int half = l >> 4;
    int q = l & 15;             // feature sub-block: features 6q..6q+5
    int n = blockIdx.x * 8 + (tid >> 5);
    if (n >= N) return;

    float di = dinv[n];
    float acc0 = 0, acc1 = 0, acc2 = 0, acc3 = 0, acc4 = 0, acc5 = 0;

    unsigned base = off[n], len = cnt[n];
    for (unsigned i0 = 0; i0 < len; i0 += 32) {
        int take = (int)(len - i0); if (take > 32) take = 32;
        nfloat2 ev = {0.0f, 0.0f};
        if (l < take)
            ev = __builtin_nontemporal_load((const nfloat2*)sorted + base + i0 + l);
        int   se = __float_as_int(ev.x);     // 0 for padded lanes
        float me = ev.y * dinv[se];          // 0 for padded lanes

        unsigned xa0, xa1, xa2, xb0, xb1, xb2, xc0, xc1, xc2, xd0, xd1, xd2;
        unsigned ya0, ya1, ya2, yb0, yb1, yb2, yc0, yc1, yc2, yd0, yd1, yd2;
        float wx0, wx1, wx2, wx3, wy0, wy1, wy2, wy3;

        #define LOADX(bb) {                                                        \
            int s0 = __shfl(se, (bb) + half, 32);                                  \
            int s1 = __shfl(se, (bb) + 2 + half, 32);                              \
            int s2 = __shfl(se, (bb) + 4 + half, 32);                              \
            int s3 = __shfl(se, (bb) + 6 + half, 32);                              \
            wx0 = __shfl(me, (bb) + half, 32);                                     \
            wx1 = __shfl(me, (bb) + 2 + half, 32);                                 \
            wx2 = __shfl(me, (bb) + 4 + half, 32);                                 \
            wx3 = __shfl(me, (bb) + 6 + half, 32);                                 \
            const unsigned* p0 = xwh + (size_t)s0 * 48 + q * 3;                    \
            const unsigned* p1 = xwh + (size_t)s1 * 48 + q * 3;                    \
            const unsigned* p2 = xwh + (size_t)s2 * 48 + q * 3;                    \
            const unsigned* p3 = xwh + (size_t)s3 * 48 + q * 3;                    \
            xa0 = p0[0]; xa1 = p0[1]; xa2 = p0[2];                                 \
            xb0 = p1[0]; xb1 = p1[1]; xb2 = p1[2];                                 \
            xc0 = p2[0]; xc1 = p2[1]; xc2 = p2[2];                                 \
            xd0 = p3[0]; xd1 = p3[1]; xd2 = p3[2]; }
        #define LOADY(bb) {                                                        \
            int s0 = __shfl(se, (bb) + half, 32);                                  \
            int s1 = __shfl(se, (bb) + 2 + half, 32);                              \
            int s2 = __shfl(se, (bb) + 4 + half, 32);                              \
            int s3 = __shfl(se, (bb) + 6 + half, 32);                              \
            wy0 = __shfl(me, (bb) + half, 32);                                     \
            wy1 = __shfl(me, (bb) + 2 + half, 32);                                 \
            wy2 = __shfl(me, (bb) + 4 + half, 32);                                 \
            wy3 = __shfl(me, (bb) + 6 + half, 32);                                 \
            const unsigned* p0 = xwh + (size_t)s0 * 48 + q * 3;                    \
            const unsigned* p1 = xwh + (size_t)s1 * 48 + q * 3;                    \
            const unsigned* p2 = xwh + (size_t)s2 * 48 + q * 3;                    \
            const unsigned* p3 = xwh + (size_t)s3 * 48 + q * 3;                    \
            ya0 = p0[0]; ya1 = p0[1]; ya2 = p0[2];                                 \
            yb0 = p1[0]; yb1 = p1[1]; yb2 = p1[2];                                 \
            yc0 = p2[0]; yc1 = p2[1]; yc2 = p2[2];                                 \
            yd0 = p3[0]; yd1 = p3[1]; yd2 = p3[2]; }
        #define CONSX() {                                                          \
            acc0 += wx0 * __uint_as_float(xa0 << 16);                              \
            acc1 += wx0 * __uint_as_float(xa0 & 0xFFFF0000u);                      \
            acc2 += wx0 * __uint_as_float(xa1 << 16);                              \
            acc3 += wx0 * __uint_as_float(xa1 & 0xFFFF0000u);                      \
            acc4 += wx0 * __uint_as_float(xa2 << 16);                              \
            acc5 += wx0 * __uint_as_float(xa2 & 0xFFFF0000u);                      \
            acc0 += wx1 * __uint_as_float(xb0 << 16);                              \
            acc1 += wx1 * __uint_as_float(xb0 & 0xFFFF0000u);                      \
            acc2 += wx1 * __uint_as_float(xb1 << 16);                              \
            acc3 += wx1 * __uint_as_float(xb1 & 0xFFFF0000u);                      \
            acc4 += wx1 * __uint_as_float(xb2 << 16);                              \
            acc5 += wx1 * __uint_as_float(xb2 & 0xFFFF0000u);                      \
            acc0 += wx2 * __uint_as_float(xc0 << 16);                              \
            acc1 += wx2 * __uint_as_float(xc0 & 0xFFFF0000u);                      \
            acc2 += wx2 * __uint_as_float(xc1 << 16);                              \
            acc3 += wx2 * __uint_as_float(xc1 & 0xFFFF0000u);                      \
            acc4 += wx2 * __uint_as_float(xc2 << 16);                              \
            acc5 += wx2 * __uint_as_float(xc2 & 0xFFFF0000u);                      \
            acc0 += wx3 * __uint_as_float(xd0 << 16);                              \
            acc1 += wx3 * __uint_as_float(xd0 & 0xFFFF0000u);                      \
            acc2 += wx3 * __uint_as_float(xd1 << 16);                              \
            acc3 += wx3 * __uint_as_float(xd1 & 0xFFFF0000u);                      \
            acc4 += wx3 * __uint_as_float(xd2 << 16);                              \
            acc5 += wx3 * __uint_as_float(xd2 & 0xFFFF0000u); }
        #define CONSY() {                                                          \
            acc0 += wy0 * __uint_as_float(ya0 << 16);                              \
            acc1 += wy0 * __uint_as_float(ya0 & 0xFFFF0000u);                      \
            acc2 += wy0 * __uint_as_float(ya1 << 16);                              \
            acc3 += wy0 * __uint_as_float(ya1 & 0xFFFF0000u);                      \
            acc4 += wy0 * __uint_as_float(ya2 << 16);                              \
            acc5 += wy0 * __uint_as_float(ya2 & 0xFFFF0000u);                      \
            acc0 += wy1 * __uint_as_float(yb0 << 16);                              \
            acc1 += wy1 * __uint_as_float(yb0 & 0xFFFF0000u);                      \
            acc2 += wy1 * __uint_as_float(yb1 << 16);                              \
            acc3 += wy1 * __uint_as_float(yb1 & 0xFFFF0000u);                      \
            acc4 += wy1 * __uint_as_float(yb2 << 16);                              \
            acc5 += wy1 * __uint_as_float(yb2 & 0xFFFF0000u);                      \
            acc0 += wy2 * __uint_as_float(yc0 << 16);                              \
            acc1 += wy2 * __uint_as_float(yc0 & 0xFFFF0000u);                      \
            acc2 += wy2 * __uint_as_float(yc1 << 16);                              \
            acc3 += wy2 * __uint_as_float(yc1 & 0xFFFF0000u);                      \
            acc4 += wy2 * __uint_as_float(yc2 << 16);                              \
            acc5 += wy2 * __uint_as_float(yc2 & 0xFFFF0000u);                      \
            acc0 += wy3 * __uint_as_float(yd0 << 16);                              \
            acc1 += wy3 * __uint_as_float(yd0 & 0xFFFF0000u);                      \
            acc2 += wy3 * __uint_as_float(yd1 << 16);                              \
            acc3 += wy3 * __uint_as_float(yd1 & 0xFFFF0000u);                      \
            acc4 += wy3 * __uint_as_float(yd2 << 16);                              \
            acc5 += wy3 * __uint_as_float(yd2 & 0xFFFF0000u); }

        LOADX(0)
        if (take > 8)  LOADY(8)
        CONSX()
        if (take > 16) LOADX(16)
        if (take > 8)  CONSY()
        if (take > 24) LOADY(24)
        if (take > 16) CONSX()
        if (take > 24) CONSY()
        #undef LOADX
        #undef LOADY
        #undef CONSX
        #undef CONSY
    }
    // fold the two halves
    acc0 += __shfl_xor(acc0, 16, 32);
    acc1 += __shfl_xor(acc1, 16, 32);
    acc2 += __shfl_xor(acc2, 16, 32);
    acc3 += __shfl_xor(acc3, 16, 32);
    acc4 += __shfl_xor(acc4, 16, 32);
    acc5 += __shfl_xor(acc5, 16, 32);
    // self-loop + di scale + bias: g_i = di*(acc_i + di*x_i) + b[f], f = q*6+i
    float g0, g1, g2, g3, g4, g5;
    {
        const unsigned* p = xwh + (size_t)n * 48 + q * 3;
        unsigned u0 = p[0], u1 = p[1], u2 = p[2];
        #define BIAS(f) ((f) < 32 ? bz[(f)] : ((f) < 64 ? br[(f) - 32] : bh[(f) - 64]))
        int f = q * 6;
        g0 = di * (acc0 + di * __uint_as_float(u0 << 16))         + BIAS(f);
        g1 = di * (acc1 + di * __uint_as_float(u0 & 0xFFFF0000u)) + BIAS(f + 1);
        g2 = di * (acc2 + di * __uint_as_float(u1 << 16))         + BIAS(f + 2);
        g3 = di * (acc3 + di * __uint_as_float(u1 & 0xFFFF0000u)) + BIAS(f + 3);
        g4 = di * (acc4 + di * __uint_as_float(u2 << 16))         + BIAS(f + 4);
        g5 = di * (acc5 + di * __uint_as_float(u2 & 0xFFFF0000u)) + BIAS(f + 5);
        #undef BIAS
    }
    // transpose to per-lane-feature layout: lane l wants feature f at (mm=f/6, ii=f%6)
    #define GATHERF(out, fexp) { int ff = (fexp); int mm = ff / 6, ii = ff % 6;            \
        float t0 = __shfl(g0, mm, 32), t1 = __shfl(g1, mm, 32), t2 = __shfl(g2, mm, 32),   \
              t3 = __shfl(g3, mm, 32), t4 = __shfl(g4, mm, 32), t5 = __shfl(g5, mm, 32);   \
        out = ii == 0 ? t0 : ii == 1 ? t1 : ii == 2 ? t2 : ii == 3 ? t3 : ii == 4 ? t4 : t5; }
    float gz, gr, gh;
    GATHERF(gz, l);
    GATHERF(gr, 32 + l);
    GATHERF(gh, 64 + l);
    #undef GATHERF

    float Hd = Hin[(size_t)n * HID + l];

    float az = Lzb[l], ar = Lrb[l];
    #pragma unroll 4
    for (int k = 0; k < 32; ++k) {
        float gzk = __shfl(gz, k, 32);
        float grk = __shfl(gr, k, 32);
        float Hk  = __shfl(Hd, k, 32);
        az += gzk * Lzw[k * 32 + l] + Hk * Lzw[(32 + k) * 32 + l];
        ar += grk * Lrw[k * 32 + l] + Hk * Lrw[(32 + k) * 32 + l];
    }
    float Z  = 1.0f / (1.0f + __expf(-az));
    float Rg = 1.0f / (1.0f + __expf(-ar));
    float HR = Hd * Rg;
    float ah = Lhb[l];
    #pragma unroll 4
    for (int k = 0; k < 32; ++k) {
        float ghk = __shfl(gh, k, 32);
        float HRk = __shfl(HR, k, 32);
        ah += ghk * Lhw[k * 32 + l] + HRk * Lhw[(32 + k) * 32 + l];
    }
    float Ht = tanhf(ah);
    float Hn = Z * Hd + (1.0f - Z) * Ht;
    float h = fmaxf(Hn, 0.0f);

    float logit = (l < 10) ? linb[l] : -INFINITY;
    #pragma unroll 4
    for (int k = 0; k < 32; ++k) {
        float hk = __shfl(h, k, 32);
        if (l < 10) logit += hk * linw[k * 10 + l];
    }
    float mx = logit;
    #pragma unroll
    for (int o = 8; o >= 1; o >>= 1) mx = fmaxf(mx, __shfl_xor(mx, o, 16));
    float ex = (l < 10) ? __expf(logit - mx) : 0.0f;
    float sum = ex;
    #pragma unroll
    for (int o = 8; o >= 1; o >>= 1) sum += __shfl_xor(sum, o, 16);
    if (l < 10) out_probs[(size_t)n * 10 + l] = ex / sum;
    out_H[(size_t)n * HID + l] = Hd;
}

extern "C" void kernel_launch(void* const* d_in, const int* in_sizes, int n_in,
                              void* d_out, int out_size, void* d_ws, size_t ws_size,
                              hipStream_t stream) {
    const float* x    = (const float*)d_in[0];
    const int*   ei   = (const int*)d_in[1];     // int32, layout [2][E]
    const float* ew   = (const float*)d_in[2];
    const float* H    = (const float*)d_in[3];
    const float* Wz   = (const float*)d_in[4];
    const float* bz   = (const float*)d_in[5];
    const float* Wr   = (const float*)d_in[6];
    const float* br   = (const float*)d_in[7];
    const float* Wh   = (const float*)d_in[8];
    const float* bh   = (const float*)d_in[9];
    const float* Lzw  = (const float*)d_in[10];
    const float* Lzb  = (const float*)d_in[11];
    const float* Lrw  = (const float*)d_in[12];
    const float* Lrb  = (const float*)d_in[13];
    const float* Lhw  = (const float*)d_in[14];
    const float* Lhb  = (const float*)d_in[15];
    const float* linw = (const float*)d_in[16];
    const float* linb = (const float*)d_in[17];

    int N = in_sizes[0] / F;
    int E = in_sizes[2];
    int nchunk = (N + CHUNK - 1) / CHUNK;   // 391 for N=100k (scan supports <=1024)

    float* ws = (float*)d_ws;
    unsigned* xwh    = (unsigned*)ws;                       // N*48 u32 (N*96 bf16)
    float2*   sorted = (float2*)(ws + (size_t)N * 48);
    float*    dinv   = ws + (size_t)N * 48 + (size_t)E * 2;
    unsigned* cnt    = (unsigned*)(dinv + N);
    unsigned* off    = cnt + N;
    unsigned* csum   = off + N;
    unsigned* cnt8   = csum + 1024;
    unsigned* pb     = cnt8 + (size_t)NCOPY * N;
    unsigned* rank   = xwh;    // overlay: E u32 (12.8MB) <= N*48 u32 (19.2MB); dead before k_gemm

    float* out_probs = (float*)d_out;
    float* out_H     = (float*)d_out + (size_t)N * 10;

    hipMemsetAsync(cnt8, 0, (size_t)NCOPY * N * sizeof(unsigned), stream);
    k_hist<<<(E + 255) / 256, 256, 0, stream>>>(ei + (size_t)E, cnt8, rank, N, E);
    k_chunksum<<<nchunk, 256, 0, stream>>>(cnt8, cnt, csum, N);
    k_scanchunks<<<1, 1024, 0, stream>>>(csum, nchunk);
    k_scanapply<<<nchunk, 256, 0, stream>>>(cnt, cnt8, csum, off, pb, N);
    k_permute<<<(E + 255) / 256, 256, 0, stream>>>(ei, ew, pb, rank, sorted, N, E);
    k_degsum<<<(N + 7) / 8, 256, 0, stream>>>(off, cnt, sorted, dinv, N);
    k_gemm<<<2048, 256, 0, stream>>>(x, Wz, Wr, Wh, xwh, N);
    k_fused<<<(N + 7) / 8, 256, 0, stream>>>(off, cnt, sorted, xwh, dinv, H,
                                             bz, br, bh, Lzw, Lzb, Lrw, Lrb, Lhw, Lhb,
                                             linw, linb, out_probs, out_H, N);
}

// Round 13
// 532.634 us; speedup vs baseline: 1.0664x; 1.0664x over previous
//
#include <hip/hip_runtime.h>
#include <cstdint>
#include <cmath>

#define HID 32
#define GATES 96  // 3*HID
#define F 128
#define CHUNK 256

typedef float nfloat2 __attribute__((ext_vector_type(2)));

__device__ inline unsigned f2b(float x) {   // f32 -> bf16 (RNE)
    unsigned u = __float_as_uint(x);
    return (u + 0x7FFFu + ((u >> 16) & 1u)) >> 16;
}

// ws layout (float units): xwh[N*48] (N*96 bf16) | sorted[E*2] | dinv[N] | cnt[N] | off[N] | csum[nchunk]
// rank[E] (u32) OVERLAYS xwh: rank dies at k_permute, before k_gemm writes xwh.

// the only atomics in the pipeline: rank[e] = old count (edge's slot in its dst segment)
__global__ __launch_bounds__(256) void k_hist(const int* __restrict__ ei_dst,
                                              unsigned* __restrict__ cnt,
                                              unsigned* __restrict__ rank, int E) {
    int e = blockIdx.x * 256 + threadIdx.x;
    if (e >= E) return;
    rank[e] = atomicAdd(&cnt[ei_dst[e]], 1u);
}

__global__ __launch_bounds__(256) void k_chunksum(const unsigned* __restrict__ cnt,
                                                  unsigned* __restrict__ csum, int N) {
    __shared__ unsigned s[256];
    int i = blockIdx.x * 256 + threadIdx.x;
    s[threadIdx.x] = (i < N) ? cnt[i] : 0u;
    __syncthreads();
    for (int off = 128; off > 0; off >>= 1) {
        if (threadIdx.x < off) s[threadIdx.x] += s[threadIdx.x + off];
        __syncthreads();
    }
    if (threadIdx.x == 0) csum[blockIdx.x] = s[0];
}

__global__ __launch_bounds__(1024) void k_scanchunks(unsigned* __restrict__ csum, int nc) {
    __shared__ unsigned s[1024];
    int t = threadIdx.x;
    unsigned v = (t < nc) ? csum[t] : 0u;
    s[t] = v;
    __syncthreads();
    for (int o = 1; o < 1024; o <<= 1) {
        unsigned x = s[t];
        if (t >= o) x += s[t - o];
        __syncthreads();
        s[t] = x;
        __syncthreads();
    }
    if (t < nc) csum[t] = s[t] - v;   // exclusive
}

__global__ __launch_bounds__(256) void k_scanapply(const unsigned* __restrict__ cnt,
                                                   const unsigned* __restrict__ csum,
                                                   unsigned* __restrict__ off, int N) {
    __shared__ unsigned s[2][256];
    int t = threadIdx.x, i = blockIdx.x * 256 + t;
    unsigned v = (i < N) ? cnt[i] : 0u;
    int cur = 0;
    s[0][t] = v;
    __syncthreads();
    for (int o = 1; o < 256; o <<= 1) {
        unsigned x = s[cur][t];
        if (t >= o) x += s[cur][t - o];
        s[cur ^ 1][t] = x;
        cur ^= 1;
        __syncthreads();
    }
    unsigned excl = s[cur][t] - v + csum[blockIdx.x];
    if (i < N) off[i] = excl;
}

// atomic-free permute: slot = off[d] + rank[e]; payload (src, raw w)
__global__ __launch_bounds__(256) void k_permute(const int* __restrict__ ei,
        const float* __restrict__ w, const unsigned* __restrict__ off,
        const unsigned* __restrict__ rank, float2* __restrict__ sorted, int E) {
    int e = blockIdx.x * 256 + threadIdx.x;
    if (e >= E) return;
    int s = ei[e];
    int d = ei[(size_t)E + e];
    unsigned p = off[d] + rank[e];
    sorted[p] = make_float2(__int_as_float(s), w[e]);
}

// dinv[n] = rsqrt(1 + sum w over CSR segment)
__global__ __launch_bounds__(256) void k_degsum(const unsigned* __restrict__ off,
        const unsigned* __restrict__ cnt, const float2* __restrict__ sorted,
        float* __restrict__ dinv, int N) {
    int l = threadIdx.x & 31;
    int n = blockIdx.x * 8 + (threadIdx.x >> 5);
    if (n >= N) return;
    unsigned base = off[n], len = cnt[n];
    float s = 0.0f;
    for (unsigned i = l; i < len; i += 32) s += sorted[base + i].y;
    #pragma unroll
    for (int o = 16; o >= 1; o >>= 1) s += __shfl_xor(s, o, 32);
    if (l == 0) dinv[n] = rsqrtf(1.0f + s);
}

// premultiply: sorted[p].y = w * dinv[src]  (removes dinv from fused's dependency chain)
__global__ __launch_bounds__(256) void k_scale(float2* __restrict__ sorted,
        const float* __restrict__ dinv, int E) {
    int p = blockIdx.x * 256 + threadIdx.x;
    if (p >= E) return;
    float2 e = sorted[p];
    e.y *= dinv[__float_as_int(e.x)];
    sorted[p] = e;
}

// xwh[n][c] (bf16) = x[n][:] @ [Wz|Wr|Wh][:, c]
#define GR 16
__global__ __launch_bounds__(256) void k_gemm(const float* __restrict__ x,
        const float* __restrict__ Wz, const float* __restrict__ Wr, const float* __restrict__ Wh,
        unsigned* __restrict__ xwh, int N) {
    __shared__ float Wl[F * GATES];
    __shared__ float xs[GR][F + 1];
    int tid = threadIdx.x;
    for (int i = tid; i < F * GATES; i += 256) {
        int k = i / GATES, c = i % GATES;
        float v;
        if (c < 32)      v = Wz[k * 32 + c];
        else if (c < 64) v = Wr[k * 32 + (c - 32)];
        else             v = Wh[k * 32 + (c - 64)];
        Wl[i] = v;
    }
    int r_local = tid / 16;
    int cb = tid % 16;
    int ntiles = (N + GR - 1) / GR;
    for (int t = blockIdx.x; t < ntiles; t += gridDim.x) {
        int row0 = t * GR;
        __syncthreads();
        for (int i = tid; i < GR * F; i += 256) {
            int r = i / F, k = i % F;
            int g = row0 + r;
            xs[r][k] = (g < N) ? x[(size_t)g * F + k] : 0.0f;
        }
        __syncthreads();
        int grow = row0 + r_local;
        if (grow < N) {
            float acc[6] = {0, 0, 0, 0, 0, 0};
            for (int k = 0; k < F; ++k) {
                float xv = xs[r_local][k];
                const float* wr = &Wl[k * GATES + cb * 6];
                #pragma unroll
                for (int j = 0; j < 6; ++j) acc[j] += xv * wr[j];
            }
            unsigned* o = xwh + (size_t)grow * 48 + cb * 3;
            o[0] = f2b(acc[0]) | (f2b(acc[1]) << 16);
            o[1] = f2b(acc[2]) | (f2b(acc[3]) << 16);
            o[2] = f2b(acc[4]) | (f2b(acc[5]) << 16);
        }
    }
}

// one 32-lane group per dst node, two 16-lane halves; half h handles edges j = h, h+2, ...
// Per step: 8B same-address meta load (L2 broadcast) -> 12B row gather -> 6 FMAs.
// No shfl in the loop; steps independent -> compiler pipelines with unroll 4.
__global__ __launch_bounds__(256, 8) void k_fused(
        const unsigned* __restrict__ off, const unsigned* __restrict__ cnt,
        const float2* __restrict__ sorted,
        const unsigned* __restrict__ xwh, const float* __restrict__ dinv, const float* __restrict__ Hin,
        const float* __restrict__ bz, const float* __restrict__ br, const float* __restrict__ bh,
        const float* __restrict__ Lzw, const float* __restrict__ Lzb,
        const float* __restrict__ Lrw, const float* __restrict__ Lrb,
        const float* __restrict__ Lhw, const float* __restrict__ Lhb,
        const float* __restrict__ linw, const float* __restrict__ linb,
        float* __restrict__ out_probs, float* __restrict__ out_H, int N) {
    int tid = threadIdx.x;
    int l = tid & 31;
    int half = l >> 4;
    int q = l & 15;             // feature sub-block: features 6q..6q+5
    int n = blockIdx.x * 8 + (tid >> 5);
    if (n >= N) return;

    float di = dinv[n];
    float acc0 = 0, acc1 = 0, acc2 = 0, acc3 = 0, acc4 = 0, acc5 = 0;

    unsigned base = off[n], len = cnt[n];
    #pragma unroll 4
    for (unsigned j = half; j < len; j += 2) {
        nfloat2 e = *((const nfloat2*)sorted + base + j);   // 16 lanes, same addr
        int   s = __float_as_int(e.x);
        float m = e.y;                                      // premultiplied w*dinv[src]
        const unsigned* p = xwh + (size_t)s * 48 + q * 3;
        unsigned u0 = p[0], u1 = p[1], u2 = p[2];
        acc0 += m * __uint_as_float(u0 << 16);
        acc1 += m * __uint_as_float(u0 & 0xFFFF0000u);
        acc2 += m * __uint_as_float(u1 << 16);
        acc3 += m * __uint_as_float(u1 & 0xFFFF0000u);
        acc4 += m * __uint_as_float(u2 << 16);
        acc5 += m * __uint_as_float(u2 & 0xFFFF0000u);
    }
    // fold the two halves
    acc0 += __shfl_xor(acc0, 16, 32);
    acc1 += __shfl_xor(acc1, 16, 32);
    acc2 += __shfl_xor(acc2, 16, 32);
    acc3 += __shfl_xor(acc3, 16, 32);
    acc4 += __shfl_xor(acc4, 16, 32);
    acc5 += __shfl_xor(acc5, 16, 32);
    // self-loop + di scale + bias: g_i = di*(acc_i + di*x_i) + b[f], f = q*6+i
    float g0, g1, g2, g3, g4, g5;
    {
        const unsigned* p = xwh + (size_t)n * 48 + q * 3;
        unsigned u0 = p[0], u1 = p[1], u2 = p[2];
        #define BIAS(f) ((f) < 32 ? bz[(f)] : ((f) < 64 ? br[(f) - 32] : bh[(f) - 64]))
        int f = q * 6;
        g0 = di * (acc0 + di * __uint_as_float(u0 << 16))         + BIAS(f);
        g1 = di * (acc1 + di * __uint_as_float(u0 & 0xFFFF0000u)) + BIAS(f + 1);
        g2 = di * (acc2 + di * __uint_as_float(u1 << 16))         + BIAS(f + 2);
        g3 = di * (acc3 + di * __uint_as_float(u1 & 0xFFFF0000u)) + BIAS(f + 3);
        g4 = di * (acc4 + di * __uint_as_float(u2 << 16))         + BIAS(f + 4);
        g5 = di * (acc5 + di * __uint_as_float(u2 & 0xFFFF0000u)) + BIAS(f + 5);
        #undef BIAS
    }
    // transpose to per-lane-feature layout: lane l wants feature f at (mm=f/6, ii=f%6)
    #define GATHERF(out, fexp) { int ff = (fexp); int mm = ff / 6, ii = ff % 6;            \
        float t0 = __shfl(g0, mm, 32), t1 = __shfl(g1, mm, 32), t2 = __shfl(g2, mm, 32),   \
              t3 = __shfl(g3, mm, 32), t4 = __shfl(g4, mm, 32), t5 = __shfl(g5, mm, 32);   \
        out = ii == 0 ? t0 : ii == 1 ? t1 : ii == 2 ? t2 : ii == 3 ? t3 : ii == 4 ? t4 : t5; }
    float gz, gr, gh;
    GATHERF(gz, l);
    GATHERF(gr, 32 + l);
    GATHERF(gh, 64 + l);
    #undef GATHERF

    float Hd = Hin[(size_t)n * HID + l];

    float az = Lzb[l], ar = Lrb[l];
    #pragma unroll 4
    for (int k = 0; k < 32; ++k) {
        float gzk = __shfl(gz, k, 32);
        float grk = __shfl(gr, k, 32);
        float Hk  = __shfl(Hd, k, 32);
        az += gzk * Lzw[k * 32 + l] + Hk * Lzw[(32 + k) * 32 + l];
        ar += grk * Lrw[k * 32 + l] + Hk * Lrw[(32 + k) * 32 + l];
    }
    float Z  = 1.0f / (1.0f + __expf(-az));
    float Rg = 1.0f / (1.0f + __expf(-ar));
    float HR = Hd * Rg;
    float ah = Lhb[l];
    #pragma unroll 4
    for (int k = 0; k < 32; ++k) {
        float ghk = __shfl(gh, k, 32);
        float HRk = __shfl(HR, k, 32);
        ah += ghk * Lhw[k * 32 + l] + HRk * Lhw[(32 + k) * 32 + l];
    }
    float Ht = tanhf(ah);
    float Hn = Z * Hd + (1.0f - Z) * Ht;
    float h = fmaxf(Hn, 0.0f);

    float logit = (l < 10) ? linb[l] : -INFINITY;
    #pragma unroll 4
    for (int k = 0; k < 32; ++k) {
        float hk = __shfl(h, k, 32);
        if (l < 10) logit += hk * linw[k * 10 + l];
    }
    float mx = logit;
    #pragma unroll
    for (int o = 8; o >= 1; o >>= 1) mx = fmaxf(mx, __shfl_xor(mx, o, 16));
    float ex = (l < 10) ? __expf(logit - mx) : 0.0f;
    float sum = ex;
    #pragma unroll
    for (int o = 8; o >= 1; o >>= 1) sum += __shfl_xor(sum, o, 16);
    if (l < 10) out_probs[(size_t)n * 10 + l] = ex / sum;
    out_H[(size_t)n * HID + l] = Hd;
}

extern "C" void kernel_launch(void* const* d_in, const int* in_sizes, int n_in,
                              void* d_out, int out_size, void* d_ws, size_t ws_size,
                              hipStream_t stream) {
    const float* x    = (const float*)d_in[0];
    const int*   ei   = (const int*)d_in[1];     // int32, layout [2][E]
    const float* ew   = (const float*)d_in[2];
    const float* H    = (const float*)d_in[3];
    const float* Wz   = (const float*)d_in[4];
    const float* bz   = (const float*)d_in[5];
    const float* Wr   = (const float*)d_in[6];
    const float* br   = (const float*)d_in[7];
    const float* Wh   = (const float*)d_in[8];
    const float* bh   = (const float*)d_in[9];
    const float* Lzw  = (const float*)d_in[10];
    const float* Lzb  = (const float*)d_in[11];
    const float* Lrw  = (const float*)d_in[12];
    const float* Lrb  = (const float*)d_in[13];
    const float* Lhw  = (const float*)d_in[14];
    const float* Lhb  = (const float*)d_in[15];
    const float* linw = (const float*)d_in[16];
    const float* linb = (const float*)d_in[17];

    int N = in_sizes[0] / F;
    int E = in_sizes[2];
    int nchunk = (N + CHUNK - 1) / CHUNK;   // 391 for N=100k (scan supports <=1024)

    float* ws = (float*)d_ws;
    unsigned* xwh    = (unsigned*)ws;                       // N*48 u32 (N*96 bf16)
    float2*   sorted = (float2*)(ws + (size_t)N * 48);
    float*    dinv   = ws + (size_t)N * 48 + (size_t)E * 2;
    unsigned* cnt    = (unsigned*)(dinv + N);
    unsigned* off    = cnt + N;
    unsigned* csum   = off + N;
    unsigned* rank   = xwh;    // overlay: E u32 (12.8MB) <= N*48 u32 (19.2MB); dead before k_gemm

    float* out_probs = (float*)d_out;
    float* out_H     = (float*)d_out + (size_t)N * 10;

    hipMemsetAsync(cnt, 0, (size_t)N * sizeof(unsigned), stream);
    k_hist<<<(E + 255) / 256, 256, 0, stream>>>(ei + (size_t)E, cnt, rank, E);
    k_chunksum<<<nchunk, 256, 0, stream>>>(cnt, csum, N);
    k_scanchunks<<<1, 1024, 0, stream>>>(csum, nchunk);
    k_scanapply<<<nchunk, 256, 0, stream>>>(cnt, csum, off, N);
    k_permute<<<(E + 255) / 256, 256, 0, stream>>>(ei, ew, off, rank, sorted, E);
    k_degsum<<<(N + 7) / 8, 256, 0, stream>>>(off, cnt, sorted, dinv, N);
    k_scale<<<(E + 255) / 256, 256, 0, stream>>>(sorted, dinv, E);
    k_gemm<<<2048, 256, 0, stream>>>(x, Wz, Wr, Wh, xwh, N);
    k_fused<<<(N + 7) / 8, 256, 0, stream>>>(off, cnt, sorted, xwh, dinv, H,
                                             bz, br, bh, Lzw, Lzb, Lrw, Lrb, Lhw, Lhb,
                                             linw, linb, out_probs, out_H, N);
}

// Round 14
// 514.992 us; speedup vs baseline: 1.1029x; 1.0343x over previous
//
#include <hip/hip_runtime.h>
#include <cstdint>
#include <cmath>

#define HID 32
#define GATES 96  // 3*HID
#define F 128
#define CHUNK 256

typedef float nfloat2 __attribute__((ext_vector_type(2)));

__device__ inline unsigned f2b(float x) {   // f32 -> bf16 (RNE)
    unsigned u = __float_as_uint(x);
    return (u + 0x7FFFu + ((u >> 16) & 1u)) >> 16;
}

// ws layout (float units): xwh[N*48] (N*96 bf16) | sorted[E*2] | dinv[N] | cnt[N] | off[N] | csum[nchunk]
// rank[E] (u32) OVERLAYS xwh: rank dies at k_permute, before k_gemm writes xwh.

// the only atomics: rank[e] = old count (edge's slot in its dst segment)
__global__ __launch_bounds__(256) void k_hist(const int* __restrict__ ei_dst,
                                              unsigned* __restrict__ cnt,
                                              unsigned* __restrict__ rank, int E) {
    int e = blockIdx.x * 256 + threadIdx.x;
    if (e >= E) return;
    rank[e] = atomicAdd(&cnt[ei_dst[e]], 1u);
}

__global__ __launch_bounds__(256) void k_chunksum(const unsigned* __restrict__ cnt,
                                                  unsigned* __restrict__ csum, int N) {
    __shared__ unsigned s[256];
    int i = blockIdx.x * 256 + threadIdx.x;
    s[threadIdx.x] = (i < N) ? cnt[i] : 0u;
    __syncthreads();
    for (int off = 128; off > 0; off >>= 1) {
        if (threadIdx.x < off) s[threadIdx.x] += s[threadIdx.x + off];
        __syncthreads();
    }
    if (threadIdx.x == 0) csum[blockIdx.x] = s[0];
}

__global__ __launch_bounds__(1024) void k_scanchunks(unsigned* __restrict__ csum, int nc) {
    __shared__ unsigned s[1024];
    int t = threadIdx.x;
    unsigned v = (t < nc) ? csum[t] : 0u;
    s[t] = v;
    __syncthreads();
    for (int o = 1; o < 1024; o <<= 1) {
        unsigned x = s[t];
        if (t >= o) x += s[t - o];
        __syncthreads();
        s[t] = x;
        __syncthreads();
    }
    if (t < nc) csum[t] = s[t] - v;   // exclusive
}

__global__ __launch_bounds__(256) void k_scanapply(const unsigned* __restrict__ cnt,
                                                   const unsigned* __restrict__ csum,
                                                   unsigned* __restrict__ off, int N) {
    __shared__ unsigned s[2][256];
    int t = threadIdx.x, i = blockIdx.x * 256 + t;
    unsigned v = (i < N) ? cnt[i] : 0u;
    int cur = 0;
    s[0][t] = v;
    __syncthreads();
    for (int o = 1; o < 256; o <<= 1) {
        unsigned x = s[cur][t];
        if (t >= o) x += s[cur][t - o];
        s[cur ^ 1][t] = x;
        cur ^= 1;
        __syncthreads();
    }
    unsigned excl = s[cur][t] - v + csum[blockIdx.x];
    if (i < N) off[i] = excl;
}

// atomic-free permute: slot = off[d] + rank[e]; payload (src, raw w)
__global__ __launch_bounds__(256) void k_permute(const int* __restrict__ ei,
        const float* __restrict__ w, const unsigned* __restrict__ off,
        const unsigned* __restrict__ rank, float2* __restrict__ sorted, int E) {
    int e = blockIdx.x * 256 + threadIdx.x;
    if (e >= E) return;
    int s = ei[e];
    int d = ei[(size_t)E + e];
    unsigned p = off[d] + rank[e];
    sorted[p] = make_float2(__int_as_float(s), w[e]);
}

// dinv[n] = rsqrt(1 + sum w over CSR segment)
__global__ __launch_bounds__(256) void k_degsum(const unsigned* __restrict__ off,
        const unsigned* __restrict__ cnt, const float2* __restrict__ sorted,
        float* __restrict__ dinv, int N) {
    int l = threadIdx.x & 31;
    int n = blockIdx.x * 8 + (threadIdx.x >> 5);
    if (n >= N) return;
    unsigned base = off[n], len = cnt[n];
    float s = 0.0f;
    for (unsigned i = l; i < len; i += 32) s += sorted[base + i].y;
    #pragma unroll
    for (int o = 16; o >= 1; o >>= 1) s += __shfl_xor(s, o, 32);
    if (l == 0) dinv[n] = rsqrtf(1.0f + s);
}

// xwh[n][c] (bf16) = dinv[n] * (x[n][:] @ [Wz|Wr|Wh][:, c])   -- dinv folded in
#define GR 16
__global__ __launch_bounds__(256) void k_gemm(const float* __restrict__ x,
        const float* __restrict__ Wz, const float* __restrict__ Wr, const float* __restrict__ Wh,
        const float* __restrict__ dinv, unsigned* __restrict__ xwh, int N) {
    __shared__ float Wl[F * GATES];
    __shared__ float xs[GR][F + 1];
    int tid = threadIdx.x;
    for (int i = tid; i < F * GATES; i += 256) {
        int k = i / GATES, c = i % GATES;
        float v;
        if (c < 32)      v = Wz[k * 32 + c];
        else if (c < 64) v = Wr[k * 32 + (c - 32)];
        else             v = Wh[k * 32 + (c - 64)];
        Wl[i] = v;
    }
    int r_local = tid / 16;
    int cb = tid % 16;
    int ntiles = (N + GR - 1) / GR;
    for (int t = blockIdx.x; t < ntiles; t += gridDim.x) {
        int row0 = t * GR;
        __syncthreads();
        for (int i = tid; i < GR * F; i += 256) {
            int r = i / F, k = i % F;
            int g = row0 + r;
            xs[r][k] = (g < N) ? x[(size_t)g * F + k] : 0.0f;
        }
        __syncthreads();
        int grow = row0 + r_local;
        if (grow < N) {
            float acc[6] = {0, 0, 0, 0, 0, 0};
            for (int k = 0; k < F; ++k) {
                float xv = xs[r_local][k];
                const float* wr = &Wl[k * GATES + cb * 6];
                #pragma unroll
                for (int j = 0; j < 6; ++j) acc[j] += xv * wr[j];
            }
            float dv = dinv[grow];
            unsigned* o = xwh + (size_t)grow * 48 + cb * 3;
            o[0] = f2b(dv * acc[0]) | (f2b(dv * acc[1]) << 16);
            o[1] = f2b(dv * acc[2]) | (f2b(dv * acc[3]) << 16);
            o[2] = f2b(dv * acc[4]) | (f2b(dv * acc[5]) << 16);
        }
    }
}

// one 32-lane group per dst node, two 16-lane halves; half h owns edges j = h, h+2, ...
// DUAL-SLOT loop: 2 edges per iteration with independent chains -> 2-4 gathers in flight.
// gate = di * (sum_e w_e * xwh_s[src] + xwh_s[n]) + b   (xwh_s rows pre-scaled by dinv)
__global__ __launch_bounds__(256, 8) void k_fused(
        const unsigned* __restrict__ off, const unsigned* __restrict__ cnt,
        const float2* __restrict__ sorted,
        const unsigned* __restrict__ xwh, const float* __restrict__ dinv, const float* __restrict__ Hin,
        const float* __restrict__ bz, const float* __restrict__ br, const float* __restrict__ bh,
        const float* __restrict__ Lzw, const float* __restrict__ Lzb,
        const float* __restrict__ Lrw, const float* __restrict__ Lrb,
        const float* __restrict__ Lhw, const float* __restrict__ Lhb,
        const float* __restrict__ linw, const float* __restrict__ linb,
        float* __restrict__ out_probs, float* __restrict__ out_H, int N) {
    int tid = threadIdx.x;
    int l = tid & 31;
    int half = l >> 4;
    int q = l & 15;             // feature sub-block: features 6q..6q+5
    int n = blockIdx.x * 8 + (tid >> 5);
    if (n >= N) return;

    float di = dinv[n];
    float acc0 = 0, acc1 = 0, acc2 = 0, acc3 = 0, acc4 = 0, acc5 = 0;

    unsigned base = off[n], len = cnt[n];
    const nfloat2* mp = (const nfloat2*)sorted + base;
    unsigned j = half;
    #pragma unroll 2
    for (; j + 2 < len; j += 4) {       // two edges per iteration, independent chains
        nfloat2 ea = mp[j];
        nfloat2 eb = mp[j + 2];
        int   sa = __float_as_int(ea.x);
        int   sb = __float_as_int(eb.x);
        float ma = ea.y;
        float mb = eb.y;
        const unsigned* pa = xwh + (size_t)sa * 48 + q * 3;
        const unsigned* pb = xwh + (size_t)sb * 48 + q * 3;
        unsigned a0 = pa[0], a1 = pa[1], a2 = pa[2];
        unsigned b0 = pb[0], b1 = pb[1], b2 = pb[2];
        acc0 += ma * __uint_as_float(a0 << 16);
        acc1 += ma * __uint_as_float(a0 & 0xFFFF0000u);
        acc2 += ma * __uint_as_float(a1 << 16);
        acc3 += ma * __uint_as_float(a1 & 0xFFFF0000u);
        acc4 += ma * __uint_as_float(a2 << 16);
        acc5 += ma * __uint_as_float(a2 & 0xFFFF0000u);
        acc0 += mb * __uint_as_float(b0 << 16);
        acc1 += mb * __uint_as_float(b0 & 0xFFFF0000u);
        acc2 += mb * __uint_as_float(b1 << 16);
        acc3 += mb * __uint_as_float(b1 & 0xFFFF0000u);
        acc4 += mb * __uint_as_float(b2 << 16);
        acc5 += mb * __uint_as_float(b2 & 0xFFFF0000u);
    }
    for (; j < len; j += 2) {           // tail (0 or 1 edge per half)
        nfloat2 e = mp[j];
        int   s = __float_as_int(e.x);
        float m = e.y;
        const unsigned* p = xwh + (size_t)s * 48 + q * 3;
        unsigned u0 = p[0], u1 = p[1], u2 = p[2];
        acc0 += m * __uint_as_float(u0 << 16);
        acc1 += m * __uint_as_float(u0 & 0xFFFF0000u);
        acc2 += m * __uint_as_float(u1 << 16);
        acc3 += m * __uint_as_float(u1 & 0xFFFF0000u);
        acc4 += m * __uint_as_float(u2 << 16);
        acc5 += m * __uint_as_float(u2 & 0xFFFF0000u);
    }
    // fold the two halves
    acc0 += __shfl_xor(acc0, 16, 32);
    acc1 += __shfl_xor(acc1, 16, 32);
    acc2 += __shfl_xor(acc2, 16, 32);
    acc3 += __shfl_xor(acc3, 16, 32);
    acc4 += __shfl_xor(acc4, 16, 32);
    acc5 += __shfl_xor(acc5, 16, 32);
    // self-loop (xwh_s[n]) + di scale + bias: g_i = di*(acc_i + xwh_s[n][f]) + b[f], f = q*6+i
    float g0, g1, g2, g3, g4, g5;
    {
        const unsigned* p = xwh + (size_t)n * 48 + q * 3;
        unsigned u0 = p[0], u1 = p[1], u2 = p[2];
        #define BIAS(f) ((f) < 32 ? bz[(f)] : ((f) < 64 ? br[(f) - 32] : bh[(f) - 64]))
        int f = q * 6;
        g0 = di * (acc0 + __uint_as_float(u0 << 16))         + BIAS(f);
        g1 = di * (acc1 + __uint_as_float(u0 & 0xFFFF0000u)) + BIAS(f + 1);
        g2 = di * (acc2 + __uint_as_float(u1 << 16))         + BIAS(f + 2);
        g3 = di * (acc3 + __uint_as_float(u1 & 0xFFFF0000u)) + BIAS(f + 3);
        g4 = di * (acc4 + __uint_as_float(u2 << 16))         + BIAS(f + 4);
        g5 = di * (acc5 + __uint_as_float(u2 & 0xFFFF0000u)) + BIAS(f + 5);
        #undef BIAS
    }
    // transpose to per-lane-feature layout: lane l wants feature f at (mm=f/6, ii=f%6)
    #define GATHERF(out, fexp) { int ff = (fexp); int mm = ff / 6, ii = ff % 6;            \
        float t0 = __shfl(g0, mm, 32), t1 = __shfl(g1, mm, 32), t2 = __shfl(g2, mm, 32),   \
              t3 = __shfl(g3, mm, 32), t4 = __shfl(g4, mm, 32), t5 = __shfl(g5, mm, 32);   \
        out = ii == 0 ? t0 : ii == 1 ? t1 : ii == 2 ? t2 : ii == 3 ? t3 : ii == 4 ? t4 : t5; }
    float gz, gr, gh;
    GATHERF(gz, l);
    GATHERF(gr, 32 + l);
    GATHERF(gh, 64 + l);
    #undef GATHERF

    float Hd = Hin[(size_t)n * HID + l];

    float az = Lzb[l], ar = Lrb[l];
    #pragma unroll 4
    for (int k = 0; k < 32; ++k) {
        float gzk = __shfl(gz, k, 32);
        float grk = __shfl(gr, k, 32);
        float Hk  = __shfl(Hd, k, 32);
        az += gzk * Lzw[k * 32 + l] + Hk * Lzw[(32 + k) * 32 + l];
        ar += grk * Lrw[k * 32 + l] + Hk * Lrw[(32 + k) * 32 + l];
    }
    float Z  = 1.0f / (1.0f + __expf(-az));
    float Rg = 1.0f / (1.0f + __expf(-ar));
    float HR = Hd * Rg;
    float ah = Lhb[l];
    #pragma unroll 4
    for (int k = 0; k < 32; ++k) {
        float ghk = __shfl(gh, k, 32);
        float HRk = __shfl(HR, k, 32);
        ah += ghk * Lhw[k * 32 + l] + HRk * Lhw[(32 + k) * 32 + l];
    }
    float Ht = tanhf(ah);
    float Hn = Z * Hd + (1.0f - Z) * Ht;
    float h = fmaxf(Hn, 0.0f);

    float logit = (l < 10) ? linb[l] : -INFINITY;
    #pragma unroll 4
    for (int k = 0; k < 32; ++k) {
        float hk = __shfl(h, k, 32);
        if (l < 10) logit += hk * linw[k * 10 + l];
    }
    float mx = logit;
    #pragma unroll
    for (int o = 8; o >= 1; o >>= 1) mx = fmaxf(mx, __shfl_xor(mx, o, 16));
    float ex = (l < 10) ? __expf(logit - mx) : 0.0f;
    float sum = ex;
    #pragma unroll
    for (int o = 8; o >= 1; o >>= 1) sum += __shfl_xor(sum, o, 16);
    if (l < 10) out_probs[(size_t)n * 10 + l] = ex / sum;
    out_H[(size_t)n * HID + l] = Hd;
}

extern "C" void kernel_launch(void* const* d_in, const int* in_sizes, int n_in,
                              void* d_out, int out_size, void* d_ws, size_t ws_size,
                              hipStream_t stream) {
    const float* x    = (const float*)d_in[0];
    const int*   ei   = (const int*)d_in[1];     // int32, layout [2][E]
    const float* ew   = (const float*)d_in[2];
    const float* H    = (const float*)d_in[3];
    const float* Wz   = (const float*)d_in[4];
    const float* bz   = (const float*)d_in[5];
    const float* Wr   = (const float*)d_in[6];
    const float* br   = (const float*)d_in[7];
    const float* Wh   = (const float*)d_in[8];
    const float* bh   = (const float*)d_in[9];
    const float* Lzw  = (const float*)d_in[10];
    const float* Lzb  = (const float*)d_in[11];
    const float* Lrw  = (const float*)d_in[12];
    const float* Lrb  = (const float*)d_in[13];
    const float* Lhw  = (const float*)d_in[14];
    const float* Lhb  = (const float*)d_in[15];
    const float* linw = (const float*)d_in[16];
    const float* linb = (const float*)d_in[17];

    int N = in_sizes[0] / F;
    int E = in_sizes[2];
    int nchunk = (N + CHUNK - 1) / CHUNK;   // 391 for N=100k (scan supports <=1024)

    float* ws = (float*)d_ws;
    unsigned* xwh    = (unsigned*)ws;                       // N*48 u32 (N*96 bf16)
    float2*   sorted = (float2*)(ws + (size_t)N * 48);
    float*    dinv   = ws + (size_t)N * 48 + (size_t)E * 2;
    unsigned* cnt    = (unsigned*)(dinv + N);
    unsigned* off    = cnt + N;
    unsigned* csum   = off + N;
    unsigned* rank   = xwh;    // overlay: E u32 (12.8MB) <= N*48 u32 (19.2MB); dead before k_gemm

    float* out_probs = (float*)d_out;
    float* out_H     = (float*)d_out + (size_t)N * 10;

    hipMemsetAsync(cnt, 0, (size_t)N * sizeof(unsigned), stream);
    k_hist<<<(E + 255) / 256, 256, 0, stream>>>(ei + (size_t)E, cnt, rank, E);
    k_chunksum<<<nchunk, 256, 0, stream>>>(cnt, csum, N);
    k_scanchunks<<<1, 1024, 0, stream>>>(csum, nchunk);
    k_scanapply<<<nchunk, 256, 0, stream>>>(cnt, csum, off, N);
    k_permute<<<(E + 255) / 256, 256, 0, stream>>>(ei, ew, off, rank, sorted, E);
    k_degsum<<<(N + 7) / 8, 256, 0, stream>>>(off, cnt, sorted, dinv, N);
    k_gemm<<<2048, 256, 0, stream>>>(x, Wz, Wr, Wh, dinv, xwh, N);
    k_fused<<<(N + 7) / 8, 256, 0, stream>>>(off, cnt, sorted, xwh, dinv, H,
                                             bz, br, bh, Lzw, Lzb, Lrw, Lrb, Lhw, Lhb,
                                             linw, linb, out_probs, out_H, N);
}